// Round 1
// baseline (228.860 us; speedup 1.0000x reference)
//
#include <hip/hip_runtime.h>

#define BATCH 8
#define CHN 128
#define HH 160
#define WW 160
#define RR 2
#define MAXOFF 5
#define NOFF 25
#define TILE 16
#define PADT (TILE + 2*RR)   /* 20 */
#define CCHUNK 8

__device__ __forceinline__ int reflect_idx(int i, int n) {
    // np.pad mode='reflect' semantics for i in [-RR, n+RR)
    if (i < 0) i = -i;
    if (i >= n) i = 2 * (n - 1) - i;
    return i;
}

__global__ __launch_bounds__(256) void costvol_kernel(
    const float* __restrict__ c1,
    const float* __restrict__ c2,
    const float* __restrict__ pw,
    float* __restrict__ out)
{
    __shared__ float tile[CCHUNK][PADT][PADT];

    const int tid = threadIdx.x;
    const int lx = tid & 15;
    const int ly = tid >> 4;

    int bidx = blockIdx.x;
    const int tx0 = (bidx % (WW / TILE)) * TILE; bidx /= (WW / TILE);
    const int ty0 = (bidx % (HH / TILE)) * TILE; bidx /= (HH / TILE);
    const int b = bidx;

    const int h = ty0 + ly;
    const int w = tx0 + lx;

    float acc[NOFF];
#pragma unroll
    for (int i = 0; i < NOFF; ++i) acc[i] = 0.f;

    const float* c1p = c1 + (size_t)b * CHN * (HH * WW) + h * WW + w;
    const float* c2b = c2 + (size_t)b * CHN * (HH * WW);

    for (int c0 = 0; c0 < CHN; c0 += CCHUNK) {
        __syncthreads();   // protect tile from previous iteration's readers
        // stage CCHUNK channels of the 20x20 reflected halo tile
        for (int idx = tid; idx < CCHUNK * PADT * PADT; idx += 256) {
            int c   = idx / (PADT * PADT);
            int rem = idx - c * (PADT * PADT);
            int ty  = rem / PADT;
            int tx  = rem - ty * PADT;
            int gr  = reflect_idx(ty0 - RR + ty, HH);
            int gc  = reflect_idx(tx0 - RR + tx, WW);
            tile[c][ty][tx] = c2b[(size_t)(c0 + c) * (HH * WW) + gr * WW + gc];
        }
        __syncthreads();

#pragma unroll
        for (int c = 0; c < CCHUNK; ++c) {
            float s = c1p[(size_t)(c0 + c) * (HH * WW)];
#pragma unroll
            for (int dy = 0; dy < MAXOFF; ++dy) {
#pragma unroll
                for (int dx = 0; dx < MAXOFF; ++dx) {
                    acc[dy * MAXOFF + dx] =
                        fmaf(s, tile[c][ly + dy][lx + dx], acc[dy * MAXOFF + dx]);
                }
            }
        }
    }

    const float a = pw[0];
    const float inv_c = 1.0f / (float)CHN;
    float* op = out + (size_t)b * NOFF * (HH * WW) + h * WW + w;
#pragma unroll
    for (int o = 0; o < NOFF; ++o) {
        float v = acc[o] * inv_c;
        op[(size_t)o * (HH * WW)] = (v >= 0.f) ? v : a * v;
    }
}

extern "C" void kernel_launch(void* const* d_in, const int* in_sizes, int n_in,
                              void* d_out, int out_size, void* d_ws, size_t ws_size,
                              hipStream_t stream) {
    const float* c1 = (const float*)d_in[0];
    const float* c2 = (const float*)d_in[1];
    const float* pw = (const float*)d_in[2];
    float* out = (float*)d_out;

    dim3 grid((WW / TILE) * (HH / TILE) * BATCH);  // 10*10*8 = 800 blocks
    dim3 block(256);
    costvol_kernel<<<grid, block, 0, stream>>>(c1, c2, pw, out);
}

// Round 2
// 157.757 us; speedup vs baseline: 1.4507x; 1.4507x over previous
//
#include <hip/hip_runtime.h>

#define BATCH 8
#define CHN 128
#define HH 160
#define WW 160
#define RR 2
#define MAXOFF 5
#define NOFF 25
#define TILE 16
#define PADT (TILE + 2*RR)       /* 20 */
#define NG 2                     /* channel groups per block */
#define RC 8                     /* channels per group per round */
#define SCH (NG*RC)              /* staged channels per round = 16 */
#define ROUNDS (CHN/(NG*RC))     /* 8 */
#define NTHREADS 512

__device__ __forceinline__ int reflect_idx(int i, int n) {
    if (i < 0) i = -i;
    if (i >= n) i = 2 * (n - 1) - i;
    return i;
}

__global__ __launch_bounds__(NTHREADS, 6) void costvol_kernel(
    const float* __restrict__ c1,
    const float* __restrict__ c2,
    const float* __restrict__ pw,
    float* __restrict__ out)
{
    // staging buffer (6400 floats = 25.6 KB), reused for the cross-group reduction
    __shared__ float lds[SCH * PADT * PADT];

    const int tid = threadIdx.x;
    const int g  = tid >> 8;      // channel group 0..1
    const int p  = tid & 255;     // pixel id within tile
    const int lx = p & 15;
    const int ly = p >> 4;

    int bidx = blockIdx.x;
    const int tx0 = (bidx % (WW / TILE)) * TILE; bidx /= (WW / TILE);
    const int ty0 = (bidx % (HH / TILE)) * TILE; bidx /= (HH / TILE);
    const int b = bidx;

    const int h = ty0 + ly;
    const int w = tx0 + lx;

    float acc[NOFF];
#pragma unroll
    for (int i = 0; i < NOFF; ++i) acc[i] = 0.f;

    const float* c1p = c1 + ((size_t)b * CHN + g * (CHN / NG)) * (HH * WW) + h * WW + w;
    const float* c2b = c2 + (size_t)b * CHN * (HH * WW);

    for (int r = 0; r < ROUNDS; ++r) {
        __syncthreads();   // protect lds from previous round's readers
        // stage SCH channels of the 20x20 reflected halo tile (both groups' channels)
        for (int idx = tid; idx < SCH * PADT * PADT; idx += NTHREADS) {
            int cc  = idx / (PADT * PADT);
            int rem = idx - cc * (PADT * PADT);
            int ty  = rem / PADT;
            int tx  = rem - ty * PADT;
            int g2  = cc >> 3;          // which group's channel
            int j   = cc & 7;
            int gr  = reflect_idx(ty0 - RR + ty, HH);
            int gc  = reflect_idx(tx0 - RR + tx, WW);
            lds[idx] = c2b[(size_t)(g2 * (CHN / NG) + r * RC + j) * (HH * WW) + gr * WW + gc];
        }
        __syncthreads();

        float s[RC];
#pragma unroll
        for (int j = 0; j < RC; ++j)
            s[j] = c1p[(size_t)(r * RC + j) * (HH * WW)];

#pragma unroll
        for (int j = 0; j < RC; ++j) {
            const float* t = &lds[(g * RC + j) * PADT * PADT];
#pragma unroll
            for (int dy = 0; dy < MAXOFF; ++dy) {
#pragma unroll
                for (int dx = 0; dx < MAXOFF; ++dx) {
                    acc[dy * MAXOFF + dx] =
                        fmaf(s[j], t[(ly + dy) * PADT + lx + dx], acc[dy * MAXOFF + dx]);
                }
            }
        }
    }

    // cross-group reduction (g1 -> g0 through LDS), then scale + PReLU + store.
    const float a = pw[0];
    const float inv_c = 1.0f / (float)CHN;
    float* op = out + (size_t)b * NOFF * (HH * WW) + h * WW + w;

    for (int o0 = 0; o0 < NOFF; o0 += 8) {
        const int K = (NOFF - o0) < 8 ? (NOFF - o0) : 8;
        __syncthreads();
        if (g == 1) {
            for (int k = 0; k < K; ++k)
                lds[k * 256 + p] = acc[o0 + k];   // [k][p] layout: conflict-free
        }
        __syncthreads();
        if (g == 0) {
            for (int k = 0; k < K; ++k) {
                float v = (acc[o0 + k] + lds[k * 256 + p]) * inv_c;
                op[(size_t)(o0 + k) * (HH * WW)] = (v >= 0.f) ? v : a * v;
            }
        }
    }
}

extern "C" void kernel_launch(void* const* d_in, const int* in_sizes, int n_in,
                              void* d_out, int out_size, void* d_ws, size_t ws_size,
                              hipStream_t stream) {
    const float* c1 = (const float*)d_in[0];
    const float* c2 = (const float*)d_in[1];
    const float* pw = (const float*)d_in[2];
    float* out = (float*)d_out;

    dim3 grid((WW / TILE) * (HH / TILE) * BATCH);  // 10*10*8 = 800 blocks
    dim3 block(NTHREADS);
    costvol_kernel<<<grid, block, 0, stream>>>(c1, c2, pw, out);
}